// Round 16
// baseline (794.556 us; speedup 1.0000x reference)
//
#include <hip/hip_runtime.h>
#include <math.h>

#define NGRAPH 64
#define NE 524288      // total edges
#define EPG 8192       // edges per graph
#define TSZ 2560       // 64 rows * 40 shorts per LDS tile half

typedef short s16x8 __attribute__((ext_vector_type(8)));
typedef float f32x4 __attribute__((ext_vector_type(4)));

__device__ inline unsigned short f2bf(float f) {
    unsigned int u = __float_as_uint(f);
    return (unsigned short)((u + 0x7FFFu + ((u >> 16) & 1u)) >> 16);
}

// ---------------- CSR build: count -> per-graph scan -> fill ------------------------------
__global__ void edge_count(const int* __restrict__ key, const float* __restrict__ mask,
                           int* __restrict__ counts) {
    int e = blockIdx.x * 256 + threadIdx.x;
    if (e < NE && (!mask || mask[e] > 0.f)) atomicAdd(&counts[key[e]], 1);
}

__global__ __launch_bounds__(512) void scan_offsets(const int* __restrict__ counts,
        int* __restrict__ offs, int* __restrict__ cursor, int nPerGraph,
        float* __restrict__ degOut) {
    __shared__ int s[512];
    const int g = blockIdx.x, t = threadIdx.x;
    int v = (t < nPerGraph) ? counts[g * nPerGraph + t] : 0;
    s[t] = v; __syncthreads();
    for (int d = 1; d < 512; d <<= 1) {
        int u = (t >= d) ? s[t - d] : 0;
        __syncthreads();
        s[t] += u;
        __syncthreads();
    }
    if (t < nPerGraph) {
        int o = g * EPG + s[t] - v;
        offs[g * nPerGraph + t] = o;
        cursor[g * nPerGraph + t] = o;
        if (degOut) degOut[g * nPerGraph + t] = (float)v;
    }
}

__global__ void edge_fill(const int* __restrict__ key, const int* __restrict__ payload,
                          const float* __restrict__ mask, int* __restrict__ cursor,
                          int* __restrict__ elist) {
    int e = blockIdx.x * 256 + threadIdx.x;
    if (e < NE && (!mask || mask[e] > 0.f)) {
        int p = atomicAdd(&cursor[key[e]], 1);
        elist[p] = payload[e];
    }
}

// ---------------- CSR gather: float4/lane, XCD-locality swizzle ---------------------------
__global__ __launch_bounds__(256) void gather_csr(
    const float* __restrict__ xfeat, int Fx,
    const int* __restrict__ offs, const int* __restrict__ cnts,
    const int* __restrict__ elist,
    float* __restrict__ out, int totRows, int rowsPerGraph)
{
    const int gid = (blockIdx.x * 256 + threadIdx.x) >> 5;
    const int lane = threadIdx.x & 31;
    const int csh = (Fx == 256) ? 1 : 0;
    const int rid = gid >> csh;
    const int c0 = (gid & ((1 << csh) - 1)) << 7;
    if (rid >= totRows) return;
    const int row = (rid & 63) * rowsPerGraph + (rid >> 6);
    const int beg = offs[row];
    const int n = cnts[row];
    const long long co = (long long)c0 + (lane << 2);
    float4 acc = make_float4(0.f, 0.f, 0.f, 0.f);
    int j = 0;
    for (; j + 4 <= n; j += 4) {
        const int n0 = elist[beg + j], n1 = elist[beg + j + 1];
        const int n2 = elist[beg + j + 2], n3 = elist[beg + j + 3];
        const float4 v0 = *(const float4*)&xfeat[(long long)n0 * Fx + co];
        const float4 v1 = *(const float4*)&xfeat[(long long)n1 * Fx + co];
        const float4 v2 = *(const float4*)&xfeat[(long long)n2 * Fx + co];
        const float4 v3 = *(const float4*)&xfeat[(long long)n3 * Fx + co];
        acc.x += v0.x + v1.x + v2.x + v3.x;
        acc.y += v0.y + v1.y + v2.y + v3.y;
        acc.z += v0.z + v1.z + v2.z + v3.z;
        acc.w += v0.w + v1.w + v2.w + v3.w;
    }
    for (; j < n; ++j) {
        const float4 v = *(const float4*)&xfeat[(long long)elist[beg + j] * Fx + co];
        acc.x += v.x; acc.y += v.y; acc.z += v.z; acc.w += v.w;
    }
    *(float4*)&out[(long long)row * Fx + co] = acc;
}

// ---------------- all 7 weight converts in ONE launch -------------------------------------
struct WSpec {
    const float* w1; const float* w2; int K1; int K2; int Nn;
    unsigned short* oh; unsigned short* ol;
};

__global__ void wconv_all(WSpec s0, WSpec s1, WSpec s2, WSpec s3, WSpec s4, WSpec s5, WSpec s6) {
    WSpec s;
    switch (blockIdx.y) {
        case 0: s = s0; break; case 1: s = s1; break; case 2: s = s2; break;
        case 3: s = s3; break; case 4: s = s4; break; case 5: s = s5; break;
        default: s = s6; break;
    }
    int idx = blockIdx.x * 256 + threadIdx.x;
    int Kt = s.K1 + s.K2;
    if (idx >= s.Nn * Kt) return;
    int n = idx / Kt, k = idx - n * Kt;
    float v = (k < s.K1) ? s.w1[(long long)k * s.Nn + n] : s.w2[(long long)(k - s.K1) * s.Nn + n];
    unsigned short h = f2bf(v);
    s.oh[idx] = h;
    s.ol[idx] = f2bf(v - __uint_as_float((unsigned int)h << 16));
}

// ---------------- split-bf16 staging (hi at base, lo at base+TSZ) -------------------------
__device__ inline void stageN_split(const float* __restrict__ src, int ldk, int k0,
                                    short* lds, int tid, const float* __restrict__ rs, int m0) {
    const int r = tid >> 2, kq = (tid & 3) << 3;
    const float* p = src + (long long)r * ldk + k0 + kq;
    float v[8];
    *(float4*)v = *(const float4*)p;
    *(float4*)(v + 4) = *(const float4*)(p + 4);
    if (rs) { float s = rs[m0 + r]; for (int i = 0; i < 8; ++i) v[i] *= s; }
    s16x8 hv, lv;
    #pragma unroll
    for (int i = 0; i < 8; ++i) {
        unsigned short h = f2bf(v[i]);
        float hf = __uint_as_float((unsigned int)h << 16);
        hv[i] = (short)h;
        lv[i] = (short)f2bf(v[i] - hf);
    }
    *(s16x8*)(lds + r * 40 + kq) = hv;
    *(s16x8*)(lds + TSZ + r * 40 + kq) = lv;
}

__device__ inline void stageT_split(const float* __restrict__ src, int ldm, int k0, int m0,
                                    short* lds, int tid) {
    const int kp = tid >> 4, mc = tid & 15;
    const int k = kp << 1;
    const float* p0 = src + (long long)(k0 + k) * ldm + m0 + mc;
    const float* p1 = p0 + ldm;
    #pragma unroll
    for (int i = 0; i < 4; ++i) {
        float a = p0[i << 4], b = p1[i << 4];
        unsigned short ha = f2bf(a), hb = f2bf(b);
        float hfa = __uint_as_float((unsigned int)ha << 16);
        float hfb = __uint_as_float((unsigned int)hb << 16);
        unsigned short la = f2bf(a - hfa), lb = f2bf(b - hfb);
        const int o = (mc + (i << 4)) * 40 + k;
        *(unsigned int*)(lds + o) = (unsigned int)ha | ((unsigned int)hb << 16);
        *(unsigned int*)(lds + o + TSZ) = (unsigned int)la | ((unsigned int)lb << 16);
    }
}

__device__ inline void stageT_hi(const float* __restrict__ src, int ldm, int k0, int m0,
                                 short* lds, int tid) {
    const int kp = tid >> 4, mc = tid & 15;
    const int k = kp << 1;
    const float* p0 = src + (long long)(k0 + k) * ldm + m0 + mc;
    const float* p1 = p0 + ldm;
    #pragma unroll
    for (int i = 0; i < 4; ++i) {
        unsigned short ha = f2bf(p0[i << 4]), hb = f2bf(p1[i << 4]);
        *(unsigned int*)(lds + (mc + (i << 4)) * 40 + k) =
            (unsigned int)ha | ((unsigned int)hb << 16);
    }
}

__device__ inline void stageW_split(const unsigned short* __restrict__ wh,
                                    const unsigned short* __restrict__ wl, int ldk,
                                    int n0, int k0, short* lds, int tid) {
    const int r = tid >> 2, kq = (tid & 3) << 3;
    *(s16x8*)(lds + r * 40 + kq) = *(const s16x8*)(wh + (long long)(n0 + r) * ldk + k0 + kq);
    *(s16x8*)(lds + TSZ + r * 40 + kq) = *(const s16x8*)(wl + (long long)(n0 + r) * ldk + k0 + kq);
}

__device__ inline void mfma_split(const short* As, const short* Bs, int wm, int wn,
                                  int l15, int quad, f32x4 (&acc)[2][2]) {
    const int ko = quad << 3;
    s16x8 ah[2], al[2], bh[2], bl[2];
    #pragma unroll
    for (int i = 0; i < 2; ++i) {
        const int ra = (wm + (i << 4) + l15) * 40 + ko;
        const int rb = (wn + (i << 4) + l15) * 40 + ko;
        ah[i] = *(const s16x8*)&As[ra];
        al[i] = *(const s16x8*)&As[TSZ + ra];
        bh[i] = *(const s16x8*)&Bs[rb];
        bl[i] = *(const s16x8*)&Bs[TSZ + rb];
    }
    #pragma unroll
    for (int mi = 0; mi < 2; ++mi)
    #pragma unroll
    for (int ni = 0; ni < 2; ++ni) {
        f32x4 c = acc[mi][ni];
        c = __builtin_amdgcn_mfma_f32_16x16x32_bf16(ah[mi], bh[ni], c, 0, 0, 0);
        c = __builtin_amdgcn_mfma_f32_16x16x32_bf16(ah[mi], bl[ni], c, 0, 0, 0);
        c = __builtin_amdgcn_mfma_f32_16x16x32_bf16(al[mi], bh[ni], c, 0, 0, 0);
        acc[mi][ni] = c;
    }
}

__device__ inline void mfma_hi(const short* As, const short* Bs, int wm, int wn,
                               int l15, int quad, f32x4 (&acc)[2][2]) {
    const int ko = quad << 3;
    s16x8 ah[2], bh[2];
    #pragma unroll
    for (int i = 0; i < 2; ++i) {
        ah[i] = *(const s16x8*)&As[(wm + (i << 4) + l15) * 40 + ko];
        bh[i] = *(const s16x8*)&Bs[(wn + (i << 4) + l15) * 40 + ko];
    }
    #pragma unroll
    for (int mi = 0; mi < 2; ++mi)
    #pragma unroll
    for (int ni = 0; ni < 2; ++ni)
        acc[mi][ni] = __builtin_amdgcn_mfma_f32_16x16x32_bf16(ah[mi], bh[ni], acc[mi][ni], 0, 0, 0);
}

__device__ inline float fro_acc(const f32x4 (&a)[2][2]) {
    float s = 0.f;
    #pragma unroll
    for (int mi = 0; mi < 2; ++mi)
    #pragma unroll
    for (int ni = 0; ni < 2; ++ni)
    #pragma unroll
    for (int r = 0; r < 4; ++r) s += a[mi][ni][r] * a[mi][ni][r];
    return s;
}

// ---------------- G1: flat C = op([A1*rs|A2] @ Wt^T + bias); 2 n-tiles per block ----------
__global__ __launch_bounds__(256) void gemm_aw(
    const float* __restrict__ A1, int K1, const float* __restrict__ A2, int K2,
    const float* __restrict__ rscale,
    const unsigned short* __restrict__ Wh, const unsigned short* __restrict__ Wl,
    const float* __restrict__ bias, float* __restrict__ C, int Nn, int doRelu)
{
    __shared__ short As[2 * TSZ], Bs[4 * TSZ];
    const int m0 = blockIdx.y << 6, n0 = blockIdx.x << 7;  // 128-wide n per block
    const int tid = threadIdx.x, lane = tid & 63, wv = tid >> 6;
    const int l15 = lane & 15, quad = lane >> 4;
    const int wm = (wv & 1) << 5, wn = (wv >> 1) << 5;
    f32x4 acc0[2][2] = {};
    f32x4 acc1[2][2] = {};
    const int Kt = K1 + K2;
    for (int k0 = 0; k0 < Kt; k0 += 32) {
        if (k0 < K1) stageN_split(A1 + (long long)m0 * K1, K1, k0, As, tid, rscale, m0);
        else         stageN_split(A2 + (long long)m0 * K2, K2, k0 - K1, As, tid, nullptr, 0);
        stageW_split(Wh, Wl, Kt, n0, k0, Bs, tid);
        stageW_split(Wh, Wl, Kt, n0 + 64, k0, Bs + 2 * TSZ, tid);
        __syncthreads();
        mfma_split(As, Bs, wm, wn, l15, quad, acc0);
        mfma_split(As, Bs + 2 * TSZ, wm, wn, l15, quad, acc1);
        __syncthreads();
    }
    #pragma unroll
    for (int half = 0; half < 2; ++half) {
        f32x4 (&acc)[2][2] = half ? acc1 : acc0;
        #pragma unroll
        for (int mi = 0; mi < 2; ++mi)
        #pragma unroll
        for (int ni = 0; ni < 2; ++ni) {
            const int col = n0 + (half << 6) + wn + (ni << 4) + l15;
            const float bv = bias ? bias[col] : 0.f;
            #pragma unroll
            for (int r = 0; r < 4; ++r) {
                const int row = m0 + wm + (mi << 4) + (quad << 2) + r;
                float v = acc[mi][ni][r] + bv;
                if (doRelu) v = fmaxf(v, 0.f);
                C[(long long)row * Nn + col] = v;
            }
        }
    }
}

// ---------------- G2: batched C = A^T B (+ fro, triangle hi-only); 2 n-tiles per block ----
__global__ __launch_bounds__(256) void gemm_tt(
    const float* __restrict__ At, const float* __restrict__ Bkn,
    float* __restrict__ C, float* __restrict__ fro,
    int Kd, int Mm, int Nn, int dual,
    long long sA, long long sB, long long sC)
{
    __shared__ short As[2 * TSZ], Bs[4 * TSZ], A2s[2 * TSZ];
    __shared__ float redf[4];
    const int z = blockIdx.x;
    const float* Ap = At + (long long)z * sA;
    const float* Bp = Bkn + (long long)z * sB;
    const int m0 = blockIdx.y << 6, n0 = blockIdx.z << 7;
    const int n0b = n0 + 64;
    const int tid = threadIdx.x, lane = tid & 63, wv = tid >> 6;
    const int l15 = lane & 15, quad = lane >> 4;
    const int wm = (wv & 1) << 5, wn = (wv >> 1) << 5;
    const int fw0 = dual ? ((m0 < n0) ? 2 : ((m0 == n0) ? 1 : 0)) : 0;
    const int fw1 = dual ? ((m0 < n0b) ? 2 : ((m0 == n0b) ? 1 : 0)) : 0;
    f32x4 acc0[2][2] = {};
    f32x4 acc1[2][2] = {};
    f32x4 accA0[2][2] = {};
    f32x4 accA1[2][2] = {};
    for (int k0 = 0; k0 < Kd; k0 += 32) {
        stageT_split(Ap, Mm, k0, m0, As, tid);
        stageT_split(Bp, Nn, k0, n0, Bs, tid);
        stageT_split(Bp, Nn, k0, n0b, Bs + 2 * TSZ, tid);
        if (fw0) stageT_hi(Ap, Mm, k0, n0, A2s, tid);
        if (fw1) stageT_hi(Ap, Mm, k0, n0b, A2s + TSZ, tid);
        __syncthreads();
        mfma_split(As, Bs, wm, wn, l15, quad, acc0);
        mfma_split(As, Bs + 2 * TSZ, wm, wn, l15, quad, acc1);
        if (fw0) mfma_hi(As, A2s, wm, wn, l15, quad, accA0);
        if (fw1) mfma_hi(As, A2s + TSZ, wm, wn, l15, quad, accA1);
        __syncthreads();
    }
    float* Cp = C + (long long)z * sC;
    #pragma unroll
    for (int half = 0; half < 2; ++half) {
        f32x4 (&acc)[2][2] = half ? acc1 : acc0;
        #pragma unroll
        for (int mi = 0; mi < 2; ++mi)
        #pragma unroll
        for (int ni = 0; ni < 2; ++ni) {
            const int col = n0 + (half << 6) + wn + (ni << 4) + l15;
            #pragma unroll
            for (int r = 0; r < 4; ++r) {
                const int row = m0 + wm + (mi << 4) + (quad << 2) + r;
                Cp[(long long)row * Nn + col] = acc[mi][ni][r];
            }
        }
    }
    if (fw0 | fw1) {
        float s = (float)fw0 * fro_acc(accA0) + (float)fw1 * fro_acc(accA1);
        for (int off = 32; off; off >>= 1) s += __shfl_xor(s, off);
        if (lane == 0) redf[wv] = s;
        __syncthreads();
        if (tid == 0) atomicAdd(&fro[z], redf[0] + redf[1] + redf[2] + redf[3]);
    }
}

// ---------------- G3: batched C = A @ B; 2 n-tiles per block ------------------------------
__global__ __launch_bounds__(256) void gemm_nt(
    const float* __restrict__ A, const float* __restrict__ Bkn, float* __restrict__ C,
    int Kd, int Nn, long long sA, long long sB, long long sC)
{
    __shared__ short As[2 * TSZ], Bs[4 * TSZ];
    const int z = blockIdx.x;
    const int m0 = blockIdx.y << 6, n0 = blockIdx.z << 7;
    const float* Ap = A + (long long)z * sA + (long long)m0 * Kd;
    const float* Bp = Bkn + (long long)z * sB;
    const int tid = threadIdx.x, lane = tid & 63, wv = tid >> 6;
    const int l15 = lane & 15, quad = lane >> 4;
    const int wm = (wv & 1) << 5, wn = (wv >> 1) << 5;
    f32x4 acc0[2][2] = {};
    f32x4 acc1[2][2] = {};
    for (int k0 = 0; k0 < Kd; k0 += 32) {
        stageN_split(Ap, Kd, k0, As, tid, nullptr, 0);
        stageT_split(Bp, Nn, k0, n0, Bs, tid);
        stageT_split(Bp, Nn, k0, n0 + 64, Bs + 2 * TSZ, tid);
        __syncthreads();
        mfma_split(As, Bs, wm, wn, l15, quad, acc0);
        mfma_split(As, Bs + 2 * TSZ, wm, wn, l15, quad, acc1);
        __syncthreads();
    }
    float* Cp = C + (long long)z * sC;
    #pragma unroll
    for (int half = 0; half < 2; ++half) {
        f32x4 (&acc)[2][2] = half ? acc1 : acc0;
        #pragma unroll
        for (int mi = 0; mi < 2; ++mi)
        #pragma unroll
        for (int ni = 0; ni < 2; ++ni) {
            const int col = n0 + (half << 6) + wn + (ni << 4) + l15;
            #pragma unroll
            for (int r = 0; r < 4; ++r) {
                const int row = m0 + wm + (mi << 4) + (quad << 2) + r;
                Cp[(long long)row * Nn + col] = acc[mi][ni][r];
            }
        }
    }
}

// ---------------- wave-per-row reductions (partials, no contended atomics) ----------------
__global__ __launch_bounds__(256) void softmax_rows_wave(
    float* __restrict__ sm, int L,
    const float* __restrict__ deg,
    float* __restrict__ rowq2, float* __restrict__ rowdq2, int totRows)
{
    const int wid = (blockIdx.x * 256 + threadIdx.x) >> 6;
    const int lane = threadIdx.x & 63;
    if (wid >= totRows) return;
    float* rowp = sm + (long long)wid * L;
    const int nv = L >> 6;
    float v[4];
    if (nv == 4) {
        float4 t = *(const float4*)&rowp[lane << 2];
        v[0] = t.x; v[1] = t.y; v[2] = t.z; v[3] = t.w;
    } else {
        float2 t = *(const float2*)&rowp[lane << 1];
        v[0] = t.x; v[1] = t.y;
    }
    float mx = v[0];
    for (int i = 1; i < nv; ++i) mx = fmaxf(mx, v[i]);
    for (int off = 32; off; off >>= 1) mx = fmaxf(mx, __shfl_xor(mx, off));
    float s = 0.f;
    for (int i = 0; i < nv; ++i) { v[i] = expf(v[i] - mx); s += v[i]; }
    for (int off = 32; off; off >>= 1) s += __shfl_xor(s, off);
    const float inv = 1.f / s;
    float q2 = 0.f;
    for (int i = 0; i < nv; ++i) { float p = v[i] * inv; v[i] = p; q2 += p * p; }
    if (nv == 4) *(float4*)&rowp[lane << 2] = make_float4(v[0], v[1], v[2], v[3]);
    else         *(float2*)&rowp[lane << 1] = make_float2(v[0], v[1]);
    for (int off = 32; off; off >>= 1) q2 += __shfl_xor(q2, off);
    if (lane == 0) { rowq2[wid] = q2; rowdq2[wid] = deg[wid] * q2; }
}

__global__ __launch_bounds__(256) void zdiag_rowsum_wave(
    float* __restrict__ adj, int K, float* __restrict__ dpool,
    float* __restrict__ rowdiag, int totRows)
{
    const int wid = (blockIdx.x * 256 + threadIdx.x) >> 6;
    const int lane = threadIdx.x & 63;
    if (wid >= totRows) return;
    const int b = wid / K;
    const int dcol = wid - b * K;
    float* rowp = adj + (long long)wid * K;
    const int nv = K >> 6;
    float s = 0.f, dval = 0.f;
    for (int q = 0; q < nv; ++q) {
        int c = lane + (q << 6);
        float v = rowp[c];
        if (c == dcol) { dval = v; rowp[c] = 0.f; v = 0.f; }
        s += v;
    }
    for (int off = 32; off; off >>= 1) s += __shfl_xor(s, off);
    if (lane == (dcol & 63)) rowdiag[wid] = dval;
    if (lane == 0) dpool[wid] = sqrtf(s) + 1e-15f;
}

__global__ __launch_bounds__(256) void norm_adj_wave(
    float* __restrict__ adj, int K, const float* __restrict__ dpool,
    float* __restrict__ rowsum, float* __restrict__ rscale, int totRows)
{
    const int wid = (blockIdx.x * 256 + threadIdx.x) >> 6;
    const int lane = threadIdx.x & 63;
    if (wid >= totRows) return;
    const int b = wid / K;
    float* rowp = adj + (long long)wid * K;
    const float inv_r = 1.f / dpool[wid];
    const int nv = K >> 6;
    float s = 0.f;
    for (int q = 0; q < nv; ++q) {
        int c = lane + (q << 6);
        float v = rowp[c] * inv_r / dpool[b * K + c];
        rowp[c] = v;
        s += v;
    }
    for (int off = 32; off; off >>= 1) s += __shfl_xor(s, off);
    if (lane == 0) { rowsum[wid] = s; rscale[wid] = 1.f / fmaxf(s, 1.f); }
}

__global__ __launch_bounds__(256) void reduce2_pergraph(
    const float* __restrict__ a, const float* __restrict__ b, int rowsPerGraph,
    float* __restrict__ outA, float* __restrict__ outB)
{
    __shared__ float redA[4], redB[4];
    const int g = blockIdx.x, t = threadIdx.x;
    float sa = 0.f, sb = 0.f;
    for (int i = t; i < rowsPerGraph; i += 256) {
        sa += a[g * rowsPerGraph + i];
        if (b) sb += b[g * rowsPerGraph + i];
    }
    for (int off = 32; off; off >>= 1) { sa += __shfl_xor(sa, off); sb += __shfl_xor(sb, off); }
    const int wv = t >> 6;
    if ((t & 63) == 0) { redA[wv] = sa; redB[wv] = sb; }
    __syncthreads();
    if (t == 0) {
        outA[g] = redA[0] + redA[1] + redA[2] + redA[3];
        if (outB) outB[g] = redB[0] + redB[1] + redB[2] + redB[3];
    }
}

// ---------------- topk: one thread per candidate, float4 rank pass, scan for pos ----------
__global__ __launch_bounds__(512) void topk_kernel(
    const float* __restrict__ x, const float* __restrict__ p, int n, int k,
    int* __restrict__ new_id, int* __restrict__ sel, float* __restrict__ gate)
{
    __shared__ float sc[512];
    __shared__ int pref[512];
    const int g = blockIdx.x, tid = threadIdx.x;
    float myScore = 0.f;
    if (tid < n) {
        const float* xr = x + (long long)(g * n + tid) * 128;
        float pn2 = 0.f, d = 0.f;
        #pragma unroll 4
        for (int f = 0; f < 128; f += 4) {
            float4 pv = *(const float4*)&p[f];
            float4 v = *(const float4*)&xr[f];
            pn2 += pv.x * pv.x + pv.y * pv.y + pv.z * pv.z + pv.w * pv.w;
            d += v.x * pv.x + v.y * pv.y + v.z * pv.z + v.w * pv.w;
        }
        myScore = d / (sqrtf(pn2) + 1e-16f);
        sc[tid] = myScore;
    }
    __syncthreads();
    int keep = 0;
    if (tid < n) {
        const float si = myScore;
        int rank = 0;
        for (int j = 0; j < n; j += 4) {
            float4 s4 = *(const float4*)&sc[j];
            rank += (s4.x > si) || (s4.x == si && (j + 0) < tid);
            rank += (s4.y > si) || (s4.y == si && (j + 1) < tid);
            rank += (s4.z > si) || (s4.z == si && (j + 2) < tid);
            rank += (s4.w > si) || (s4.w == si && (j + 3) < tid);
        }
        keep = rank < k;
    }
    pref[tid] = keep;
    __syncthreads();
    for (int d = 1; d < 512; d <<= 1) {
        int u = (tid >= d) ? pref[tid - d] : 0;
        __syncthreads();
        pref[tid] += u;
        __syncthreads();
    }
    if (tid < n) {
        if (keep) {
            int pos = pref[tid] - 1;
            new_id[g * n + tid] = g * k + pos;
            sel[g * k + pos] = g * n + tid;
            gate[g * k + pos] = tanhf(myScore);
        } else new_id[g * n + tid] = -1;
    }
}

__global__ void gather_gate(const float* __restrict__ x, const int* __restrict__ sel,
                            const float* __restrict__ gate, float* __restrict__ out, int rows) {
    int t = blockIdx.x * blockDim.x + threadIdx.x;
    int r = t >> 5, q = (t & 31) << 2;
    if (r >= rows) return;
    float4 v = *(const float4*)&x[(long long)sel[r] * 128 + q];
    float gt = gate[r];
    v.x *= gt; v.y *= gt; v.z *= gt; v.w *= gt;
    *(float4*)&out[(long long)r * 128 + q] = v;
}

__global__ void remap_edges_count(const int* __restrict__ s, const int* __restrict__ d,
                                  const float* __restrict__ m, const int* __restrict__ new_id,
                                  int* __restrict__ so, int* __restrict__ do_,
                                  float* __restrict__ mo, int* __restrict__ counts) {
    int e = blockIdx.x * blockDim.x + threadIdx.x;
    if (e >= NE) return;
    int ns = new_id[s[e]], nd = new_id[d[e]];
    bool v = (ns >= 0) && (nd >= 0) && (m ? (m[e] > 0.f) : true);
    so[e] = v ? ns : 0; do_[e] = v ? nd : 0; mo[e] = v ? 1.f : 0.f;
    if (v) atomicAdd(&counts[nd], 1);
}

__global__ void readout_part(const float* __restrict__ x, int k,
                             float* __restrict__ pmax, float* __restrict__ psum) {
    int g = blockIdx.x, seg = blockIdx.y, f = threadIdx.x;
    int per = k >> 2;
    int r0 = seg * per;
    float mx0 = -INFINITY, mx1 = -INFINITY, sm0 = 0.f, sm1 = 0.f;
    int r = r0;
    for (; r + 2 <= r0 + per; r += 2) {
        float v0 = x[(long long)(g * k + r) * 128 + f];
        float v1 = x[(long long)(g * k + r + 1) * 128 + f];
        mx0 = fmaxf(mx0, v0); sm0 += v0;
        mx1 = fmaxf(mx1, v1); sm1 += v1;
    }
    for (; r < r0 + per; ++r) { float v = x[(long long)(g * k + r) * 128 + f]; mx0 = fmaxf(mx0, v); sm0 += v; }
    pmax[(g * 4 + seg) * 128 + f] = fmaxf(mx0, mx1);
    psum[(g * 4 + seg) * 128 + f] = sm0 + sm1;
}

__global__ void readout_comb(const float* __restrict__ pmax, const float* __restrict__ psum,
                             int k, float* __restrict__ sxsum) {
    int g = blockIdx.x, f = threadIdx.x;
    float mx = -INFINITY, sm = 0.f;
    #pragma unroll
    for (int s = 0; s < 4; ++s) {
        mx = fmaxf(mx, pmax[(g * 4 + s) * 128 + f]);
        sm += psum[(g * 4 + s) * 128 + f];
    }
    sxsum[g * 256 + f] += mx;
    sxsum[g * 256 + 128 + f] += sm / k;
}

__global__ void mc_o_write(const float* __restrict__ accs, float* __restrict__ out) {
    __shared__ float rm[2], ro[2];
    int t = threadIdx.x;          // 128
    int wvi = t >> 6, lane = t & 63;
    const float* acc = accs + wvi * 256;
    float sqrtk = wvi ? sqrtf(128.f) : 16.f;
    float numv = acc[lane], denv = acc[64 + lane], trv = acc[128 + lane], frov = acc[192 + lane];
    float mcb = numv / (denv + 1e-15f);
    float ssn = sqrtf(frov) + 1e-15f;
    float ob = sqrtf(fmaxf(frov / (ssn * ssn) - 2.f * trv / (ssn * sqrtk) + 1.f, 0.f));
    for (int off = 32; off; off >>= 1) { mcb += __shfl_down(mcb, off); ob += __shfl_down(ob, off); }
    if (lane == 0) { rm[wvi] = mcb; ro[wvi] = ob; }
    __syncthreads();
    if (t == 0) {
        out[640] = -(rm[0] + rm[1]) / 64.f;
        out[641] = (ro[0] + ro[1]) / 64.f;
    }
}

__global__ void mean_lin(const float* __restrict__ xd, const float* __restrict__ W,
                         const float* __restrict__ bias, float* __restrict__ xg, int nNodes) {
    __shared__ float meanv[128];
    int b = blockIdx.x, t = threadIdx.x;
    float s = 0.f;
    for (int n = 0; n < nNodes; n++) s += xd[(long long)(b * nNodes + n) * 128 + t];
    meanv[t] = s / nNodes; __syncthreads();
    float acc = bias[t];
    for (int i = 0; i < 128; i++) acc += meanv[i] * W[i * 128 + t];
    xg[b * 128 + t] = fmaxf(acc, 0.f);
}

__global__ void final_head(const float* __restrict__ sxsum, const float* __restrict__ w11,
                           const float* __restrict__ b11, const float* __restrict__ xg,
                           const float* __restrict__ w2, const float* __restrict__ b2,
                           float* __restrict__ outLogits) {
    __shared__ float sin_[256];
    __shared__ float cat[256];
    int b = blockIdx.x, t = threadIdx.x; // 128
    sin_[t] = sxsum[b * 256 + t];
    sin_[t + 128] = sxsum[b * 256 + 128 + t];
    __syncthreads();
    float acc = b11[t];
    for (int i = 0; i < 256; i++) acc += sin_[i] * w11[i * 128 + t];
    cat[t] = fmaxf(acc, 0.f);
    cat[128 + t] = xg[b * 128 + t];
    __syncthreads();
    if (t < 10) {
        float a = b2[t];
        for (int i = 0; i < 256; i++) a += cat[i] * w2[i * 10 + t];
        outLogits[b * 10 + t] = a;
    }
}

// ------------------------------------------------------------------------------------------
extern "C" void kernel_launch(void* const* d_in, const int* in_sizes, int n_in,
                              void* d_out, int out_size, void* d_ws, size_t ws_size,
                              hipStream_t stream) {
    const float* x         = (const float*)d_in[0];
    const int*   src       = (const int*)d_in[1];
    const int*   dst       = (const int*)d_in[2];
    const float* conv0_wr  = (const float*)d_in[3];
    const float* conv0_wrt = (const float*)d_in[4];
    const float* conv0_b   = (const float*)d_in[5];
    const float* sc2_wr    = (const float*)d_in[6];
    const float* sc2_wrt   = (const float*)d_in[7];
    const float* sc2_b     = (const float*)d_in[8];
    const float* sc3_wr    = (const float*)d_in[9];
    const float* sc3_wrt   = (const float*)d_in[10];
    const float* sc3_b     = (const float*)d_in[11];
    const float* sg1_wr    = (const float*)d_in[12];
    const float* sg1_wrt   = (const float*)d_in[13];
    const float* sg1_b     = (const float*)d_in[14];
    const float* sg2_wr    = (const float*)d_in[15];
    const float* sg2_wrt   = (const float*)d_in[16];
    const float* sg2_b     = (const float*)d_in[17];
    const float* pool0_w   = (const float*)d_in[18];
    const float* pool0_b   = (const float*)d_in[19];
    const float* pool1_w   = (const float*)d_in[20];
    const float* pool1_b   = (const float*)d_in[21];
    const float* p1        = (const float*)d_in[22];
    const float* p2        = (const float*)d_in[23];
    const float* p3        = (const float*)d_in[24];
    const float* l11_w     = (const float*)d_in[25];
    const float* l11_b     = (const float*)d_in[26];
    const float* l1_w      = (const float*)d_in[27];
    const float* l1_b      = (const float*)d_in[28];
    const float* l2_w      = (const float*)d_in[29];
    const float* l2_b      = (const float*)d_in[30];
    float* out = (float*)d_out;

    char* w = (char*)d_ws;
    const unsigned long long MBy = 1ull << 20;
    float* x0    = (float*)(w + 0);           // 16 MB
    float* BIG1  = (float*)(w + 16 * MBy);    // 32 MB
    float* BIG2  = (float*)(w + 48 * MBy);    // 32 MB
    float* agg   = (float*)(w + 80 * MBy);    // 16 MB
    float* outx1 = (float*)(w + 96 * MBy);    // 8 MB
    float* adj1  = (float*)(w + 104 * MBy);   // 16 MB
    int*   s1    = (int*)(w + 120 * MBy);
    int*   d1    = (int*)(w + 122 * MBy);
    float* m1    = (float*)(w + 124 * MBy);
    int*   s2e   = (int*)(w + 126 * MBy);
    int*   d2e   = (int*)(w + 128 * MBy);
    float* m2e   = (float*)(w + 130 * MBy);
    char*  misc  = w + 132 * MBy;
    float* score = (float*)(misc);
    int*   sel   = (int*)(misc + 128 * 1024);
    float* gate  = (float*)(misc + 192 * 1024);
    int*   newid = (int*)(misc + 256 * 1024);
    float* deg   = (float*)(misc + 384 * 1024);
    float* dpool = (float*)(misc + 512 * 1024);
    float* rowsum2 = (float*)(misc + 576 * 1024);
    float* rscale2 = (float*)(misc + 640 * 1024);
    float* dpool2  = (float*)(misc + 704 * 1024);
    float* rowsum3 = (float*)(misc + 736 * 1024);
    float* rscale3 = (float*)(misc + 768 * 1024);
    float* accs    = (float*)(misc + 800 * 1024);
    float* sxsum   = (float*)(misc + 900 * 1024);
    float* xg      = (float*)(misc + 964 * 1024);

    unsigned short* wt_sg1h   = (unsigned short*)(misc + 1024 * 1024);
    unsigned short* wt_sg1l   = wt_sg1h + 32768;
    unsigned short* wt_sg2h   = wt_sg1l + 32768;
    unsigned short* wt_sg2l   = wt_sg2h + 32768;
    unsigned short* wt_pool0h = wt_sg2l + 32768;
    unsigned short* wt_pool0l = wt_pool0h + 32768;
    unsigned short* wt_pool1h = wt_pool0l + 32768;
    unsigned short* wt_pool1l = wt_pool1h + 32768;
    unsigned short* wt_c0h    = wt_pool1l + 32768;
    unsigned short* wt_c0l    = wt_c0h + 32768;
    unsigned short* wt_sc2h   = wt_c0l + 32768;
    unsigned short* wt_sc2l   = wt_sc2h + 32768;
    unsigned short* wt_sc3h   = wt_sc2l + 32768;
    unsigned short* wt_sc3l   = wt_sc3h + 32768;

    float* pmax = (float*)(misc + 2048 * 1024);
    float* psum = pmax + 32768;

    float* rowq2  = score;
    float* rowdq2 = (float*)newid;
    float* rowdiag = (float*)sel;

    float* s_sm  = BIG1;
    float* Tbuf  = BIG2;
    float* xd1   = BIG2;
    float* AX    = BIG2 + 2 * 1024 * 1024;
    float* s2sm  = BIG2 + 4 * 1024 * 1024;
    float* T2    = BIG2 + 6 * 1024 * 1024;
    float* outx2 = BIG1;
    float* adj2b = BIG1 + 1024 * 1024;
    float* xd2   = BIG1 + 2 * 1024 * 1024;
    float* sxA   = BIG1 + 3 * 1024 * 1024;
    float* sxE   = BIG1 + 5 * 1024 * 1024;
    float* sxB   = x0;
    float* sxC   = x0 + 2 * 1024 * 1024;
    float* sxD   = x0 + 3 * 1024 * 1024;

    char* adjc = (char*)adj1;
    int* elA  = (int*)(adjc + 0);
    int* elB  = (int*)(adjc + 2 * MBy);
    int* cntA = (int*)(adjc + 4 * MBy);
    int* offA = (int*)(adjc + 4 * MBy + 256 * 1024);
    int* curA = (int*)(adjc + 4 * MBy + 512 * 1024);
    int* cntB = (int*)(adjc + 4 * MBy + 768 * 1024);
    int* offB = (int*)(adjc + 5 * MBy);
    int* curB = (int*)(adjc + 5 * MBy + 256 * 1024);
    char* aggc = (char*)agg;
    int* elC  = (int*)(aggc + 8 * MBy);
    int* elD  = (int*)(aggc + 10 * MBy);
    int* cntC = (int*)(aggc + 12 * MBy);
    int* offC = (int*)(aggc + 12 * MBy + 256 * 1024);
    int* curC = (int*)(aggc + 12 * MBy + 512 * 1024);
    int* cntD = (int*)(aggc + 13 * MBy);
    int* offD = (int*)(aggc + 13 * MBy + 256 * 1024);
    int* curD = (int*)(aggc + 13 * MBy + 512 * 1024);

    hipMemsetAsync(accs, 0, 520 * sizeof(float), stream);
    hipMemsetAsync(sxsum, 0, 16384 * sizeof(float), stream);
    hipMemsetAsync(cntA, 0, 32768 * sizeof(int), stream);
    hipMemsetAsync(cntB, 0, 32768 * sizeof(int), stream);

    {
        WSpec a{sg1_wr, sg1_wrt, 128, 128, 128, wt_sg1h, wt_sg1l};
        WSpec b{sg2_wr, sg2_wrt, 128, 128, 128, wt_sg2h, wt_sg2l};
        WSpec c{pool0_w, nullptr, 128, 0, 256, wt_pool0h, wt_pool0l};
        WSpec d{pool1_w, nullptr, 128, 0, 128, wt_pool1h, wt_pool1l};
        WSpec e{conv0_wr, conv0_wrt, 128, 128, 128, wt_c0h, wt_c0l};
        WSpec f{sc2_wr, sc2_wrt, 128, 128, 128, wt_sc2h, wt_sc2l};
        WSpec g{sc3_wr, sc3_wrt, 128, 128, 128, wt_sc3h, wt_sc3l};
        wconv_all<<<dim3(128, 7), 256, 0, stream>>>(a, b, c, d, e, f, g);
    }

    edge_count<<<2048, 256, 0, stream>>>(dst, nullptr, cntA);
    edge_count<<<2048, 256, 0, stream>>>(src, nullptr, cntB);
    scan_offsets<<<64, 512, 0, stream>>>(cntA, offA, curA, 512, nullptr);
    scan_offsets<<<64, 512, 0, stream>>>(cntB, offB, curB, 512, deg);
    edge_fill<<<2048, 256, 0, stream>>>(dst, src, nullptr, curA, elA);
    edge_fill<<<2048, 256, 0, stream>>>(src, dst, nullptr, curB, elB);

    // ---- conv0 (split-bf16) ----
    gather_csr<<<4096, 256, 0, stream>>>(x, 128, offA, cntA, elA, agg, 32768, 512);
    gemm_aw<<<dim3(1, 512), 256, 0, stream>>>(agg, 128, x, 128, nullptr, wt_c0h, wt_c0l,
        conv0_b, x0, 128, 1);

    // ---- dense branch, pool 1 ----
    gemm_aw<<<dim3(2, 512), 256, 0, stream>>>(x0, 128, nullptr, 0, nullptr, wt_pool0h, wt_pool0l,
        pool0_b, s_sm, 256, 0);
    softmax_rows_wave<<<8192, 256, 0, stream>>>(s_sm, 256, deg, rowq2, rowdq2, 32768);
    reduce2_pergraph<<<64, 256, 0, stream>>>(rowq2, rowdq2, 512, accs + 128, accs + 64);
    gather_csr<<<8192, 256, 0, stream>>>(s_sm, 256, offB, cntB, elB, Tbuf, 32768, 512);
    gemm_tt<<<dim3(64, 4, 1), 256, 0, stream>>>(s_sm, x0, outx1, nullptr, 512, 256, 128, 0,
        512 * 256, 512 * 128, 256 * 128);
    gemm_tt<<<dim3(64, 4, 2), 256, 0, stream>>>(s_sm, Tbuf, adj1, accs + 192, 512, 256, 256, 1,
        512 * 256, 512 * 256, 256 * 256);
    zdiag_rowsum_wave<<<4096, 256, 0, stream>>>(adj1, 256, dpool, rowdiag, 16384);
    reduce2_pergraph<<<64, 256, 0, stream>>>(rowdiag, nullptr, 256, accs + 0, nullptr);
    norm_adj_wave<<<4096, 256, 0, stream>>>(adj1, 256, dpool, rowsum2, rscale2, 16384);
    // sage1
    gemm_nt<<<dim3(64, 4, 1), 256, 0, stream>>>(adj1, outx1, AX, 256, 128,
        256 * 256, 256 * 128, 256 * 128);
    gemm_aw<<<dim3(1, 256), 256, 0, stream>>>(AX, 128, outx1, 128, rscale2, wt_sg1h, wt_sg1l,
        sg1_b, xd1, 128, 1);
    // pool 2
    gemm_aw<<<dim3(1, 256), 256, 0, stream>>>(xd1, 128, nullptr, 0, nullptr, wt_pool1h, wt_pool1l,
        pool1_b, s2sm, 128, 0);
    softmax_rows_wave<<<4096, 256, 0, stream>>>(s2sm, 128, rowsum2, rowq2, rowdq2, 16384);
    reduce2_pergraph<<<64, 256, 0, stream>>>(rowq2, rowdq2, 256, accs + 384, accs + 320);
    gemm_nt<<<dim3(64, 4, 1), 256, 0, stream>>>(adj1, s2sm, T2, 256, 128,
        256 * 256, 256 * 128, 256 * 128);
    gemm_tt<<<dim3(64, 2, 1), 256, 0, stream>>>(s2sm, xd1, outx2, nullptr, 256, 128, 128, 0,
        256 * 128, 256 * 128, 128 * 128);
    gemm_tt<<<dim3(64, 2, 1), 256, 0, stream>>>(s2sm, T2, adj2b, accs + 448, 256, 128, 128, 1,
        256 * 128, 256 * 128, 128 * 128);
    zdiag_rowsum_wave<<<2048, 256, 0, stream>>>(adj2b, 128, dpool2, rowdiag, 8192);
    reduce2_pergraph<<<64, 256, 0, stream>>>(rowdiag, nullptr, 128, accs + 256, nullptr);
    norm_adj_wave<<<2048, 256, 0, stream>>>(adj2b, 128, dpool2, rowsum3, rscale3, 8192);
    // sage2 + head
    gemm_nt<<<dim3(64, 2, 1), 256, 0, stream>>>(adj2b, outx2, AX, 128, 128,
        128 * 128, 128 * 128, 128 * 128);
    gemm_aw<<<dim3(1, 128), 256, 0, stream>>>(AX, 128, outx2, 128, rscale3, wt_sg2h, wt_sg2l,
        sg2_b, xd2, 128, 0);
    mean_lin<<<64, 128, 0, stream>>>(xd2, l1_w, l1_b, xg, 128);
    mc_o_write<<<1, 128, 0, stream>>>(accs, out);

    // ---- sparse branch ----
    topk_kernel<<<64, 512, 0, stream>>>(x0, p1, 512, 256, newid, sel, gate);
    gather_gate<<<2048, 256, 0, stream>>>(x0, sel, gate, sxA, 16384);
    hipMemsetAsync(cntC, 0, 16384 * sizeof(int), stream);
    remap_edges_count<<<2048, 256, 0, stream>>>(src, dst, nullptr, newid, s1, d1, m1, cntC);
    readout_part<<<dim3(64, 4), 128, 0, stream>>>(sxA, 256, pmax, psum);
    readout_comb<<<64, 128, 0, stream>>>(pmax, psum, 256, sxsum);
    scan_offsets<<<64, 512, 0, stream>>>(cntC, offC, curC, 256, nullptr);
    edge_fill<<<2048, 256, 0, stream>>>(d1, s1, m1, curC, elC);
    gather_csr<<<2048, 256, 0, stream>>>(sxA, 128, offC, cntC, elC, agg, 16384, 256);
    gemm_aw<<<dim3(1, 256), 256, 0, stream>>>(agg, 128, sxA, 128, nullptr, wt_sc2h, wt_sc2l,
        sc2_b, sxB, 128, 1);
    topk_kernel<<<64, 512, 0, stream>>>(sxB, p2, 256, 128, newid, sel, gate);
    gather_gate<<<1024, 256, 0, stream>>>(sxB, sel, gate, sxC, 8192);
    hipMemsetAsync(cntD, 0, 8192 * sizeof(int), stream);
    remap_edges_count<<<2048, 256, 0, stream>>>(s1, d1, m1, newid, s2e, d2e, m2e, cntD);
    readout_part<<<dim3(64, 4), 128, 0, stream>>>(sxC, 128, pmax, psum);
    readout_comb<<<64, 128, 0, stream>>>(pmax, psum, 128, sxsum);
    scan_offsets<<<64, 512, 0, stream>>>(cntD, offD, curD, 128, nullptr);
    edge_fill<<<2048, 256, 0, stream>>>(d2e, s2e, m2e, curD, elD);
    gather_csr<<<1024, 256, 0, stream>>>(sxC, 128, offD, cntD, elD, agg, 8192, 128);
    gemm_aw<<<dim3(1, 128), 256, 0, stream>>>(agg, 128, sxC, 128, nullptr, wt_sc3h, wt_sc3l,
        sc3_b, sxD, 128, 1);
    topk_kernel<<<64, 512, 0, stream>>>(sxD, p3, 128, 64, newid, sel, gate);
    gather_gate<<<512, 256, 0, stream>>>(sxD, sel, gate, sxE, 4096);
    readout_part<<<dim3(64, 4), 128, 0, stream>>>(sxE, 64, pmax, psum);
    readout_comb<<<64, 128, 0, stream>>>(pmax, psum, 64, sxsum);

    final_head<<<64, 128, 0, stream>>>(sxsum, l11_w, l11_b, xg, l2_w, l2_b, out);
}

// Round 17
// 661.973 us; speedup vs baseline: 1.2003x; 1.2003x over previous
//
#include <hip/hip_runtime.h>
#include <math.h>

#define NGRAPH 64
#define NE 524288      // total edges
#define EPG 8192       // edges per graph
#define TSZ 2560       // 64 rows * 40 shorts per LDS tile half

typedef short s16x8 __attribute__((ext_vector_type(8)));
typedef float f32x4 __attribute__((ext_vector_type(4)));

__device__ inline unsigned short f2bf(float f) {
    unsigned int u = __float_as_uint(f);
    return (unsigned short)((u + 0x7FFFu + ((u >> 16) & 1u)) >> 16);
}

// ---------------- CSR build (L0: both directions in one launch) ---------------------------
__global__ void edge_count2(const int* __restrict__ keyA, int* __restrict__ cntA,
                            const int* __restrict__ keyB, int* __restrict__ cntB) {
    int e = blockIdx.x * 256 + threadIdx.x;
    if (e >= NE) return;
    if (blockIdx.y == 0) atomicAdd(&cntA[keyA[e]], 1);
    else                 atomicAdd(&cntB[keyB[e]], 1);
}

__device__ inline void scan_body(const int* __restrict__ counts, int* __restrict__ offs,
                                 int* __restrict__ cursor, int nPerGraph,
                                 float* __restrict__ degOut, int* s) {
    const int g = blockIdx.x, t = threadIdx.x;
    int v = (t < nPerGraph) ? counts[g * nPerGraph + t] : 0;
    s[t] = v; __syncthreads();
    for (int d = 1; d < 512; d <<= 1) {
        int u = (t >= d) ? s[t - d] : 0;
        __syncthreads();
        s[t] += u;
        __syncthreads();
    }
    if (t < nPerGraph) {
        int o = g * EPG + s[t] - v;
        offs[g * nPerGraph + t] = o;
        cursor[g * nPerGraph + t] = o;
        if (degOut) degOut[g * nPerGraph + t] = (float)v;
    }
}

__global__ __launch_bounds__(512) void scan_offsets(const int* __restrict__ counts,
        int* __restrict__ offs, int* __restrict__ cursor, int nPerGraph,
        float* __restrict__ degOut) {
    __shared__ int s[512];
    scan_body(counts, offs, cursor, nPerGraph, degOut, s);
}

__global__ __launch_bounds__(512) void scan_offsets2(
        const int* __restrict__ cA, int* __restrict__ oA, int* __restrict__ uA,
        const int* __restrict__ cB, int* __restrict__ oB, int* __restrict__ uB,
        int nPerGraph, float* __restrict__ degB) {
    __shared__ int s[512];
    if (blockIdx.y == 0) scan_body(cA, oA, uA, nPerGraph, nullptr, s);
    else                 scan_body(cB, oB, uB, nPerGraph, degB, s);
}

__global__ void edge_fill(const int* __restrict__ key, const int* __restrict__ payload,
                          const float* __restrict__ mask, int* __restrict__ cursor,
                          int* __restrict__ elist) {
    int e = blockIdx.x * 256 + threadIdx.x;
    if (e < NE && (!mask || mask[e] > 0.f)) {
        int p = atomicAdd(&cursor[key[e]], 1);
        elist[p] = payload[e];
    }
}

__global__ void edge_fill2(const int* __restrict__ kA, const int* __restrict__ pA,
                           int* __restrict__ uA, int* __restrict__ eA,
                           const int* __restrict__ kB, const int* __restrict__ pB,
                           int* __restrict__ uB, int* __restrict__ eB) {
    int e = blockIdx.x * 256 + threadIdx.x;
    if (e >= NE) return;
    if (blockIdx.y == 0) { int p = atomicAdd(&uA[kA[e]], 1); eA[p] = pA[e]; }
    else                 { int p = atomicAdd(&uB[kB[e]], 1); eB[p] = pB[e]; }
}

// ---------------- CSR gather: float4/lane, XCD-locality swizzle ---------------------------
__global__ __launch_bounds__(256) void gather_csr(
    const float* __restrict__ xfeat, int Fx,
    const int* __restrict__ offs, const int* __restrict__ cnts,
    const int* __restrict__ elist,
    float* __restrict__ out, int totRows, int rowsPerGraph)
{
    const int gid = (blockIdx.x * 256 + threadIdx.x) >> 5;
    const int lane = threadIdx.x & 31;
    const int csh = (Fx == 256) ? 1 : 0;
    const int rid = gid >> csh;
    const int c0 = (gid & ((1 << csh) - 1)) << 7;
    if (rid >= totRows) return;
    const int row = (rid & 63) * rowsPerGraph + (rid >> 6);
    const int beg = offs[row];
    const int n = cnts[row];
    const long long co = (long long)c0 + (lane << 2);
    float4 acc = make_float4(0.f, 0.f, 0.f, 0.f);
    int j = 0;
    for (; j + 4 <= n; j += 4) {
        const int n0 = elist[beg + j], n1 = elist[beg + j + 1];
        const int n2 = elist[beg + j + 2], n3 = elist[beg + j + 3];
        const float4 v0 = *(const float4*)&xfeat[(long long)n0 * Fx + co];
        const float4 v1 = *(const float4*)&xfeat[(long long)n1 * Fx + co];
        const float4 v2 = *(const float4*)&xfeat[(long long)n2 * Fx + co];
        const float4 v3 = *(const float4*)&xfeat[(long long)n3 * Fx + co];
        acc.x += v0.x + v1.x + v2.x + v3.x;
        acc.y += v0.y + v1.y + v2.y + v3.y;
        acc.z += v0.z + v1.z + v2.z + v3.z;
        acc.w += v0.w + v1.w + v2.w + v3.w;
    }
    for (; j < n; ++j) {
        const float4 v = *(const float4*)&xfeat[(long long)elist[beg + j] * Fx + co];
        acc.x += v.x; acc.y += v.y; acc.z += v.z; acc.w += v.w;
    }
    *(float4*)&out[(long long)row * Fx + co] = acc;
}

// ---------------- all 7 weight converts in ONE launch -------------------------------------
struct WSpec {
    const float* w1; const float* w2; int K1; int K2; int Nn;
    unsigned short* oh; unsigned short* ol;
};

__global__ void wconv_all(WSpec s0, WSpec s1, WSpec s2, WSpec s3, WSpec s4, WSpec s5, WSpec s6) {
    WSpec s;
    switch (blockIdx.y) {
        case 0: s = s0; break; case 1: s = s1; break; case 2: s = s2; break;
        case 3: s = s3; break; case 4: s = s4; break; case 5: s = s5; break;
        default: s = s6; break;
    }
    int idx = blockIdx.x * 256 + threadIdx.x;
    int Kt = s.K1 + s.K2;
    if (idx >= s.Nn * Kt) return;
    int n = idx / Kt, k = idx - n * Kt;
    float v = (k < s.K1) ? s.w1[(long long)k * s.Nn + n] : s.w2[(long long)(k - s.K1) * s.Nn + n];
    unsigned short h = f2bf(v);
    s.oh[idx] = h;
    s.ol[idx] = f2bf(v - __uint_as_float((unsigned int)h << 16));
}

// ---------------- split-bf16 staging (hi at base, lo at base+TSZ) -------------------------
__device__ inline void stageN_split(const float* __restrict__ src, int ldk, int k0,
                                    short* lds, int tid, const float* __restrict__ rs, int m0) {
    const int r = tid >> 2, kq = (tid & 3) << 3;
    const float* p = src + (long long)r * ldk + k0 + kq;
    float v[8];
    *(float4*)v = *(const float4*)p;
    *(float4*)(v + 4) = *(const float4*)(p + 4);
    if (rs) { float s = rs[m0 + r]; for (int i = 0; i < 8; ++i) v[i] *= s; }
    s16x8 hv, lv;
    #pragma unroll
    for (int i = 0; i < 8; ++i) {
        unsigned short h = f2bf(v[i]);
        float hf = __uint_as_float((unsigned int)h << 16);
        hv[i] = (short)h;
        lv[i] = (short)f2bf(v[i] - hf);
    }
    *(s16x8*)(lds + r * 40 + kq) = hv;
    *(s16x8*)(lds + TSZ + r * 40 + kq) = lv;
}

__device__ inline void stageT_split(const float* __restrict__ src, int ldm, int k0, int m0,
                                    short* lds, int tid) {
    const int kp = tid >> 4, mc = tid & 15;
    const int k = kp << 1;
    const float* p0 = src + (long long)(k0 + k) * ldm + m0 + mc;
    const float* p1 = p0 + ldm;
    #pragma unroll
    for (int i = 0; i < 4; ++i) {
        float a = p0[i << 4], b = p1[i << 4];
        unsigned short ha = f2bf(a), hb = f2bf(b);
        float hfa = __uint_as_float((unsigned int)ha << 16);
        float hfb = __uint_as_float((unsigned int)hb << 16);
        unsigned short la = f2bf(a - hfa), lb = f2bf(b - hfb);
        const int o = (mc + (i << 4)) * 40 + k;
        *(unsigned int*)(lds + o) = (unsigned int)ha | ((unsigned int)hb << 16);
        *(unsigned int*)(lds + o + TSZ) = (unsigned int)la | ((unsigned int)lb << 16);
    }
}

__device__ inline void stageT_hi(const float* __restrict__ src, int ldm, int k0, int m0,
                                 short* lds, int tid) {
    const int kp = tid >> 4, mc = tid & 15;
    const int k = kp << 1;
    const float* p0 = src + (long long)(k0 + k) * ldm + m0 + mc;
    const float* p1 = p0 + ldm;
    #pragma unroll
    for (int i = 0; i < 4; ++i) {
        unsigned short ha = f2bf(p0[i << 4]), hb = f2bf(p1[i << 4]);
        *(unsigned int*)(lds + (mc + (i << 4)) * 40 + k) =
            (unsigned int)ha | ((unsigned int)hb << 16);
    }
}

__device__ inline void stageW_split(const unsigned short* __restrict__ wh,
                                    const unsigned short* __restrict__ wl, int ldk,
                                    int n0, int k0, short* lds, int tid) {
    const int r = tid >> 2, kq = (tid & 3) << 3;
    *(s16x8*)(lds + r * 40 + kq) = *(const s16x8*)(wh + (long long)(n0 + r) * ldk + k0 + kq);
    *(s16x8*)(lds + TSZ + r * 40 + kq) = *(const s16x8*)(wl + (long long)(n0 + r) * ldk + k0 + kq);
}

__device__ inline void mfma_split(const short* As, const short* Bs, int wm, int wn,
                                  int l15, int quad, f32x4 (&acc)[2][2]) {
    const int ko = quad << 3;
    s16x8 ah[2], al[2], bh[2], bl[2];
    #pragma unroll
    for (int i = 0; i < 2; ++i) {
        const int ra = (wm + (i << 4) + l15) * 40 + ko;
        const int rb = (wn + (i << 4) + l15) * 40 + ko;
        ah[i] = *(const s16x8*)&As[ra];
        al[i] = *(const s16x8*)&As[TSZ + ra];
        bh[i] = *(const s16x8*)&Bs[rb];
        bl[i] = *(const s16x8*)&Bs[TSZ + rb];
    }
    #pragma unroll
    for (int mi = 0; mi < 2; ++mi)
    #pragma unroll
    for (int ni = 0; ni < 2; ++ni) {
        f32x4 c = acc[mi][ni];
        c = __builtin_amdgcn_mfma_f32_16x16x32_bf16(ah[mi], bh[ni], c, 0, 0, 0);
        c = __builtin_amdgcn_mfma_f32_16x16x32_bf16(ah[mi], bl[ni], c, 0, 0, 0);
        c = __builtin_amdgcn_mfma_f32_16x16x32_bf16(al[mi], bh[ni], c, 0, 0, 0);
        acc[mi][ni] = c;
    }
}

__device__ inline void mfma_hi(const short* As, const short* Bs, int wm, int wn,
                               int l15, int quad, f32x4 (&acc)[2][2]) {
    const int ko = quad << 3;
    s16x8 ah[2], bh[2];
    #pragma unroll
    for (int i = 0; i < 2; ++i) {
        ah[i] = *(const s16x8*)&As[(wm + (i << 4) + l15) * 40 + ko];
        bh[i] = *(const s16x8*)&Bs[(wn + (i << 4) + l15) * 40 + ko];
    }
    #pragma unroll
    for (int mi = 0; mi < 2; ++mi)
    #pragma unroll
    for (int ni = 0; ni < 2; ++ni)
        acc[mi][ni] = __builtin_amdgcn_mfma_f32_16x16x32_bf16(ah[mi], bh[ni], acc[mi][ni], 0, 0, 0);
}

// ---------------- G1: flat C = op([A1*rs|A2] @ Wt^T + bias), split-bf16 -------------------
__global__ __launch_bounds__(256) void gemm_aw(
    const float* __restrict__ A1, int K1, const float* __restrict__ A2, int K2,
    const float* __restrict__ rscale,
    const unsigned short* __restrict__ Wh, const unsigned short* __restrict__ Wl,
    const float* __restrict__ bias, float* __restrict__ C, int Nn, int doRelu)
{
    __shared__ short As[2 * TSZ], Bs[2 * TSZ];
    const int m0 = blockIdx.y << 6, n0 = blockIdx.x << 6;
    const int tid = threadIdx.x, lane = tid & 63, wv = tid >> 6;
    const int l15 = lane & 15, quad = lane >> 4;
    const int wm = (wv & 1) << 5, wn = (wv >> 1) << 5;
    f32x4 acc[2][2] = {};
    const int Kt = K1 + K2;
    for (int k0 = 0; k0 < Kt; k0 += 32) {
        if (k0 < K1) stageN_split(A1 + (long long)m0 * K1, K1, k0, As, tid, rscale, m0);
        else         stageN_split(A2 + (long long)m0 * K2, K2, k0 - K1, As, tid, nullptr, 0);
        stageW_split(Wh, Wl, Kt, n0, k0, Bs, tid);
        __syncthreads();
        mfma_split(As, Bs, wm, wn, l15, quad, acc);
        __syncthreads();
    }
    #pragma unroll
    for (int mi = 0; mi < 2; ++mi)
    #pragma unroll
    for (int ni = 0; ni < 2; ++ni) {
        const int col = n0 + wn + (ni << 4) + l15;
        const float bv = bias ? bias[col] : 0.f;
        #pragma unroll
        for (int r = 0; r < 4; ++r) {
            const int row = m0 + wm + (mi << 4) + (quad << 2) + r;
            float v = acc[mi][ni][r] + bv;
            if (doRelu) v = fmaxf(v, 0.f);
            C[(long long)row * Nn + col] = v;
        }
    }
}

// ---------------- G2: batched C = A^T B (+ fro via symmetric-triangle hi-only) ------------
__global__ __launch_bounds__(256) void gemm_tt(
    const float* __restrict__ At, const float* __restrict__ Bkn,
    float* __restrict__ C, float* __restrict__ fro,
    int Kd, int Mm, int Nn, int dual,
    long long sA, long long sB, long long sC)
{
    __shared__ short As[2 * TSZ], Bs[2 * TSZ], A2s[TSZ];
    __shared__ float redf[4];
    const int z = blockIdx.x;
    const float* Ap = At + (long long)z * sA;
    const float* Bp = Bkn + (long long)z * sB;
    const int m0 = blockIdx.y << 6, n0 = blockIdx.z << 6;
    const int tid = threadIdx.x, lane = tid & 63, wv = tid >> 6;
    const int l15 = lane & 15, quad = lane >> 4;
    const int wm = (wv & 1) << 5, wn = (wv >> 1) << 5;
    const int fw = dual ? ((m0 < n0) ? 2 : ((m0 == n0) ? 1 : 0)) : 0;
    f32x4 acc[2][2] = {};
    f32x4 accA[2][2] = {};
    for (int k0 = 0; k0 < Kd; k0 += 32) {
        stageT_split(Ap, Mm, k0, m0, As, tid);
        stageT_split(Bp, Nn, k0, n0, Bs, tid);
        if (fw) stageT_hi(Ap, Mm, k0, n0, A2s, tid);
        __syncthreads();
        mfma_split(As, Bs, wm, wn, l15, quad, acc);
        if (fw) mfma_hi(As, A2s, wm, wn, l15, quad, accA);
        __syncthreads();
    }
    float* Cp = C + (long long)z * sC;
    #pragma unroll
    for (int mi = 0; mi < 2; ++mi)
    #pragma unroll
    for (int ni = 0; ni < 2; ++ni) {
        const int col = n0 + wn + (ni << 4) + l15;
        #pragma unroll
        for (int r = 0; r < 4; ++r) {
            const int row = m0 + wm + (mi << 4) + (quad << 2) + r;
            Cp[(long long)row * Nn + col] = acc[mi][ni][r];
        }
    }
    if (fw) {
        float s = 0.f;
        #pragma unroll
        for (int mi = 0; mi < 2; ++mi)
        #pragma unroll
        for (int ni = 0; ni < 2; ++ni)
        #pragma unroll
        for (int r = 0; r < 4; ++r) s += accA[mi][ni][r] * accA[mi][ni][r];
        s *= (float)fw;
        for (int off = 32; off; off >>= 1) s += __shfl_xor(s, off);
        if (lane == 0) redf[wv] = s;
        __syncthreads();
        if (tid == 0) atomicAdd(&fro[z], redf[0] + redf[1] + redf[2] + redf[3]);
    }
}

// ---------------- G3: batched C = A @ B, graph on blockIdx.x ------------------------------
__global__ __launch_bounds__(256) void gemm_nt(
    const float* __restrict__ A, const float* __restrict__ Bkn, float* __restrict__ C,
    int Kd, int Nn, long long sA, long long sB, long long sC)
{
    __shared__ short As[2 * TSZ], Bs[2 * TSZ];
    const int z = blockIdx.x;
    const int m0 = blockIdx.y << 6, n0 = blockIdx.z << 6;
    const float* Ap = A + (long long)z * sA + (long long)m0 * Kd;
    const float* Bp = Bkn + (long long)z * sB;
    const int tid = threadIdx.x, lane = tid & 63, wv = tid >> 6;
    const int l15 = lane & 15, quad = lane >> 4;
    const int wm = (wv & 1) << 5, wn = (wv >> 1) << 5;
    f32x4 acc[2][2] = {};
    for (int k0 = 0; k0 < Kd; k0 += 32) {
        stageN_split(Ap, Kd, k0, As, tid, nullptr, 0);
        stageT_split(Bp, Nn, k0, n0, Bs, tid);
        __syncthreads();
        mfma_split(As, Bs, wm, wn, l15, quad, acc);
        __syncthreads();
    }
    float* Cp = C + (long long)z * sC;
    #pragma unroll
    for (int mi = 0; mi < 2; ++mi)
    #pragma unroll
    for (int ni = 0; ni < 2; ++ni) {
        const int col = n0 + wn + (ni << 4) + l15;
        #pragma unroll
        for (int r = 0; r < 4; ++r) {
            const int row = m0 + wm + (mi << 4) + (quad << 2) + r;
            Cp[(long long)row * Nn + col] = acc[mi][ni][r];
        }
    }
}

// ---------------- wave-per-row reductions (partials, no contended atomics) ----------------
__global__ __launch_bounds__(256) void softmax_rows_wave(
    float* __restrict__ sm, int L,
    const float* __restrict__ deg,
    float* __restrict__ rowq2, float* __restrict__ rowdq2, int totRows)
{
    const int wid = (blockIdx.x * 256 + threadIdx.x) >> 6;
    const int lane = threadIdx.x & 63;
    if (wid >= totRows) return;
    float* rowp = sm + (long long)wid * L;
    const int nv = L >> 6;
    float v[4];
    if (nv == 4) {
        float4 t = *(const float4*)&rowp[lane << 2];
        v[0] = t.x; v[1] = t.y; v[2] = t.z; v[3] = t.w;
    } else {
        float2 t = *(const float2*)&rowp[lane << 1];
        v[0] = t.x; v[1] = t.y;
    }
    float mx = v[0];
    for (int i = 1; i < nv; ++i) mx = fmaxf(mx, v[i]);
    for (int off = 32; off; off >>= 1) mx = fmaxf(mx, __shfl_xor(mx, off));
    float s = 0.f;
    for (int i = 0; i < nv; ++i) { v[i] = expf(v[i] - mx); s += v[i]; }
    for (int off = 32; off; off >>= 1) s += __shfl_xor(s, off);
    const float inv = 1.f / s;
    float q2 = 0.f;
    for (int i = 0; i < nv; ++i) { float p = v[i] * inv; v[i] = p; q2 += p * p; }
    if (nv == 4) *(float4*)&rowp[lane << 2] = make_float4(v[0], v[1], v[2], v[3]);
    else         *(float2*)&rowp[lane << 1] = make_float2(v[0], v[1]);
    for (int off = 32; off; off >>= 1) q2 += __shfl_xor(q2, off);
    if (lane == 0) { rowq2[wid] = q2; rowdq2[wid] = deg[wid] * q2; }
}

__global__ __launch_bounds__(256) void zdiag_rowsum_wave(
    float* __restrict__ adj, int K, float* __restrict__ dpool,
    float* __restrict__ rowdiag, int totRows)
{
    const int wid = (blockIdx.x * 256 + threadIdx.x) >> 6;
    const int lane = threadIdx.x & 63;
    if (wid >= totRows) return;
    const int b = wid / K;
    const int dcol = wid - b * K;
    float* rowp = adj + (long long)wid * K;
    const int nv = K >> 6;
    float s = 0.f, dval = 0.f;
    for (int q = 0; q < nv; ++q) {
        int c = lane + (q << 6);
        float v = rowp[c];
        if (c == dcol) { dval = v; rowp[c] = 0.f; v = 0.f; }
        s += v;
    }
    for (int off = 32; off; off >>= 1) s += __shfl_xor(s, off);
    if (lane == (dcol & 63)) rowdiag[wid] = dval;
    if (lane == 0) dpool[wid] = sqrtf(s) + 1e-15f;
}

__global__ __launch_bounds__(256) void norm_adj_wave(
    float* __restrict__ adj, int K, const float* __restrict__ dpool,
    float* __restrict__ rowsum, float* __restrict__ rscale, int totRows)
{
    const int wid = (blockIdx.x * 256 + threadIdx.x) >> 6;
    const int lane = threadIdx.x & 63;
    if (wid >= totRows) return;
    const int b = wid / K;
    float* rowp = adj + (long long)wid * K;
    const float inv_r = 1.f / dpool[wid];
    const int nv = K >> 6;
    float s = 0.f;
    for (int q = 0; q < nv; ++q) {
        int c = lane + (q << 6);
        float v = rowp[c] * inv_r / dpool[b * K + c];
        rowp[c] = v;
        s += v;
    }
    for (int off = 32; off; off >>= 1) s += __shfl_xor(s, off);
    if (lane == 0) { rowsum[wid] = s; rscale[wid] = 1.f / fmaxf(s, 1.f); }
}

__global__ __launch_bounds__(256) void reduce2_pergraph(
    const float* __restrict__ a, const float* __restrict__ b, int rowsPerGraph,
    float* __restrict__ outA, float* __restrict__ outB)
{
    __shared__ float redA[4], redB[4];
    const int g = blockIdx.x, t = threadIdx.x;
    float sa = 0.f, sb = 0.f;
    for (int i = t; i < rowsPerGraph; i += 256) {
        sa += a[g * rowsPerGraph + i];
        if (b) sb += b[g * rowsPerGraph + i];
    }
    for (int off = 32; off; off >>= 1) { sa += __shfl_xor(sa, off); sb += __shfl_xor(sb, off); }
    const int wv = t >> 6;
    if ((t & 63) == 0) { redA[wv] = sa; redB[wv] = sb; }
    __syncthreads();
    if (t == 0) {
        outA[g] = redA[0] + redA[1] + redA[2] + redA[3];
        if (outB) outB[g] = redB[0] + redB[1] + redB[2] + redB[3];
    }
}

// ---------------- topk: one thread per candidate, float4 rank pass, scan for pos ----------
__global__ __launch_bounds__(512) void topk_kernel(
    const float* __restrict__ x, const float* __restrict__ p, int n, int k,
    int* __restrict__ new_id, int* __restrict__ sel, float* __restrict__ gate)
{
    __shared__ float sc[512];
    __shared__ int pref[512];
    const int g = blockIdx.x, tid = threadIdx.x;
    float myScore = 0.f;
    if (tid < n) {
        const float* xr = x + (long long)(g * n + tid) * 128;
        float pn2 = 0.f, d = 0.f;
        #pragma unroll 4
        for (int f = 0; f < 128; f += 4) {
            float4 pv = *(const float4*)&p[f];
            float4 v = *(const float4*)&xr[f];
            pn2 += pv.x * pv.x + pv.y * pv.y + pv.z * pv.z + pv.w * pv.w;
            d += v.x * pv.x + v.y * pv.y + v.z * pv.z + v.w * pv.w;
        }
        myScore = d / (sqrtf(pn2) + 1e-16f);
        sc[tid] = myScore;
    }
    __syncthreads();
    int keep = 0;
    if (tid < n) {
        const float si = myScore;
        int rank = 0;
        for (int j = 0; j < n; j += 4) {
            float4 s4 = *(const float4*)&sc[j];
            rank += (s4.x > si) || (s4.x == si && (j + 0) < tid);
            rank += (s4.y > si) || (s4.y == si && (j + 1) < tid);
            rank += (s4.z > si) || (s4.z == si && (j + 2) < tid);
            rank += (s4.w > si) || (s4.w == si && (j + 3) < tid);
        }
        keep = rank < k;
    }
    pref[tid] = keep;
    __syncthreads();
    for (int d = 1; d < 512; d <<= 1) {
        int u = (tid >= d) ? pref[tid - d] : 0;
        __syncthreads();
        pref[tid] += u;
        __syncthreads();
    }
    if (tid < n) {
        if (keep) {
            int pos = pref[tid] - 1;
            new_id[g * n + tid] = g * k + pos;
            sel[g * k + pos] = g * n + tid;
            gate[g * k + pos] = tanhf(myScore);
        } else new_id[g * n + tid] = -1;
    }
}

__global__ void gather_gate(const float* __restrict__ x, const int* __restrict__ sel,
                            const float* __restrict__ gate, float* __restrict__ out, int rows) {
    int t = blockIdx.x * blockDim.x + threadIdx.x;
    int r = t >> 5, q = (t & 31) << 2;
    if (r >= rows) return;
    float4 v = *(const float4*)&x[(long long)sel[r] * 128 + q];
    float gt = gate[r];
    v.x *= gt; v.y *= gt; v.z *= gt; v.w *= gt;
    *(float4*)&out[(long long)r * 128 + q] = v;
}

__global__ void remap_edges_count(const int* __restrict__ s, const int* __restrict__ d,
                                  const float* __restrict__ m, const int* __restrict__ new_id,
                                  int* __restrict__ so, int* __restrict__ do_,
                                  float* __restrict__ mo, int* __restrict__ counts) {
    int e = blockIdx.x * blockDim.x + threadIdx.x;
    if (e >= NE) return;
    int ns = new_id[s[e]], nd = new_id[d[e]];
    bool v = (ns >= 0) && (nd >= 0) && (m ? (m[e] > 0.f) : true);
    so[e] = v ? ns : 0; do_[e] = v ? nd : 0; mo[e] = v ? 1.f : 0.f;
    if (v) atomicAdd(&counts[nd], 1);
}

__global__ void readout_part(const float* __restrict__ x, int k,
                             float* __restrict__ pmax, float* __restrict__ psum) {
    int g = blockIdx.x, seg = blockIdx.y, f = threadIdx.x;
    int per = k >> 2;
    int r0 = seg * per;
    float mx0 = -INFINITY, mx1 = -INFINITY, sm0 = 0.f, sm1 = 0.f;
    int r = r0;
    for (; r + 2 <= r0 + per; r += 2) {
        float v0 = x[(long long)(g * k + r) * 128 + f];
        float v1 = x[(long long)(g * k + r + 1) * 128 + f];
        mx0 = fmaxf(mx0, v0); sm0 += v0;
        mx1 = fmaxf(mx1, v1); sm1 += v1;
    }
    for (; r < r0 + per; ++r) { float v = x[(long long)(g * k + r) * 128 + f]; mx0 = fmaxf(mx0, v); sm0 += v; }
    pmax[(g * 4 + seg) * 128 + f] = fmaxf(mx0, mx1);
    psum[(g * 4 + seg) * 128 + f] = sm0 + sm1;
}

__global__ void readout_comb(const float* __restrict__ pmax, const float* __restrict__ psum,
                             int k, float* __restrict__ sxsum) {
    int g = blockIdx.x, f = threadIdx.x;
    float mx = -INFINITY, sm = 0.f;
    #pragma unroll
    for (int s = 0; s < 4; ++s) {
        mx = fmaxf(mx, pmax[(g * 4 + s) * 128 + f]);
        sm += psum[(g * 4 + s) * 128 + f];
    }
    sxsum[g * 256 + f] += mx;
    sxsum[g * 256 + 128 + f] += sm / k;
}

__global__ void mean_lin(const float* __restrict__ xd, const float* __restrict__ W,
                         const float* __restrict__ bias, float* __restrict__ xg, int nNodes) {
    __shared__ float meanv[128];
    int b = blockIdx.x, t = threadIdx.x;
    float s = 0.f;
    for (int n = 0; n < nNodes; n++) s += xd[(long long)(b * nNodes + n) * 128 + t];
    meanv[t] = s / nNodes; __syncthreads();
    float acc = bias[t];
    for (int i = 0; i < 128; i++) acc += meanv[i] * W[i * 128 + t];
    xg[b * 128 + t] = fmaxf(acc, 0.f);
}

// final head with mc/o scalar epilogue fused into block 0
__global__ void final_head(const float* __restrict__ sxsum, const float* __restrict__ w11,
                           const float* __restrict__ b11, const float* __restrict__ xg,
                           const float* __restrict__ w2, const float* __restrict__ b2,
                           const float* __restrict__ accs, float* __restrict__ out) {
    __shared__ float sin_[256];
    __shared__ float cat[256];
    __shared__ float rm[2], ro[2];
    int b = blockIdx.x, t = threadIdx.x; // 128
    if (b == 0) {
        int wvi = t >> 6, lane = t & 63;
        const float* acc = accs + wvi * 256;
        float sqrtk = wvi ? sqrtf(128.f) : 16.f;
        float numv = acc[lane], denv = acc[64 + lane], trv = acc[128 + lane], frov = acc[192 + lane];
        float mcb = numv / (denv + 1e-15f);
        float ssn = sqrtf(frov) + 1e-15f;
        float ob = sqrtf(fmaxf(frov / (ssn * ssn) - 2.f * trv / (ssn * sqrtk) + 1.f, 0.f));
        for (int off = 32; off; off >>= 1) { mcb += __shfl_down(mcb, off); ob += __shfl_down(ob, off); }
        if (lane == 0) { rm[wvi] = mcb; ro[wvi] = ob; }
        __syncthreads();
        if (t == 0) {
            out[640] = -(rm[0] + rm[1]) / 64.f;
            out[641] = (ro[0] + ro[1]) / 64.f;
        }
    }
    sin_[t] = sxsum[b * 256 + t];
    sin_[t + 128] = sxsum[b * 256 + 128 + t];
    __syncthreads();
    float acc = b11[t];
    for (int i = 0; i < 256; i++) acc += sin_[i] * w11[i * 128 + t];
    cat[t] = fmaxf(acc, 0.f);
    cat[128 + t] = xg[b * 128 + t];
    __syncthreads();
    if (t < 10) {
        float a = b2[t];
        for (int i = 0; i < 256; i++) a += cat[i] * w2[i * 10 + t];
        out[b * 10 + t] = a;
    }
}

// ------------------------------------------------------------------------------------------
extern "C" void kernel_launch(void* const* d_in, const int* in_sizes, int n_in,
                              void* d_out, int out_size, void* d_ws, size_t ws_size,
                              hipStream_t stream) {
    const float* x         = (const float*)d_in[0];
    const int*   src       = (const int*)d_in[1];
    const int*   dst       = (const int*)d_in[2];
    const float* conv0_wr  = (const float*)d_in[3];
    const float* conv0_wrt = (const float*)d_in[4];
    const float* conv0_b   = (const float*)d_in[5];
    const float* sc2_wr    = (const float*)d_in[6];
    const float* sc2_wrt   = (const float*)d_in[7];
    const float* sc2_b     = (const float*)d_in[8];
    const float* sc3_wr    = (const float*)d_in[9];
    const float* sc3_wrt   = (const float*)d_in[10];
    const float* sc3_b     = (const float*)d_in[11];
    const float* sg1_wr    = (const float*)d_in[12];
    const float* sg1_wrt   = (const float*)d_in[13];
    const float* sg1_b     = (const float*)d_in[14];
    const float* sg2_wr    = (const float*)d_in[15];
    const float* sg2_wrt   = (const float*)d_in[16];
    const float* sg2_b     = (const float*)d_in[17];
    const float* pool0_w   = (const float*)d_in[18];
    const float* pool0_b   = (const float*)d_in[19];
    const float* pool1_w   = (const float*)d_in[20];
    const float* pool1_b   = (const float*)d_in[21];
    const float* p1        = (const float*)d_in[22];
    const float* p2        = (const float*)d_in[23];
    const float* p3        = (const float*)d_in[24];
    const float* l11_w     = (const float*)d_in[25];
    const float* l11_b     = (const float*)d_in[26];
    const float* l1_w      = (const float*)d_in[27];
    const float* l1_b      = (const float*)d_in[28];
    const float* l2_w      = (const float*)d_in[29];
    const float* l2_b      = (const float*)d_in[30];
    float* out = (float*)d_out;

    char* w = (char*)d_ws;
    const unsigned long long MBy = 1ull << 20;
    float* x0    = (float*)(w + 0);           // 16 MB
    float* BIG1  = (float*)(w + 16 * MBy);    // 32 MB
    float* BIG2  = (float*)(w + 48 * MBy);    // 32 MB
    float* agg   = (float*)(w + 80 * MBy);    // 16 MB
    float* outx1 = (float*)(w + 96 * MBy);    // 8 MB
    float* adj1  = (float*)(w + 104 * MBy);   // 16 MB
    int*   s1    = (int*)(w + 120 * MBy);
    int*   d1    = (int*)(w + 122 * MBy);
    float* m1    = (float*)(w + 124 * MBy);
    int*   s2e   = (int*)(w + 126 * MBy);
    int*   d2e   = (int*)(w + 128 * MBy);
    float* m2e   = (float*)(w + 130 * MBy);
    char*  misc  = w + 132 * MBy;
    float* score = (float*)(misc);
    int*   sel   = (int*)(misc + 128 * 1024);
    float* gate  = (float*)(misc + 192 * 1024);
    int*   newid = (int*)(misc + 256 * 1024);
    float* deg   = (float*)(misc + 384 * 1024);
    float* dpool = (float*)(misc + 512 * 1024);
    float* rowsum2 = (float*)(misc + 576 * 1024);
    float* rscale2 = (float*)(misc + 640 * 1024);
    float* dpool2  = (float*)(misc + 704 * 1024);
    float* rowsum3 = (float*)(misc + 736 * 1024);
    float* rscale3 = (float*)(misc + 768 * 1024);
    float* accs    = (float*)(misc + 800 * 1024);
    float* sxsum   = (float*)(misc + 900 * 1024);
    float* xg      = (float*)(misc + 964 * 1024);

    unsigned short* wt_sg1h   = (unsigned short*)(misc + 1024 * 1024);
    unsigned short* wt_sg1l   = wt_sg1h + 32768;
    unsigned short* wt_sg2h   = wt_sg1l + 32768;
    unsigned short* wt_sg2l   = wt_sg2h + 32768;
    unsigned short* wt_pool0h = wt_sg2l + 32768;
    unsigned short* wt_pool0l = wt_pool0h + 32768;
    unsigned short* wt_pool1h = wt_pool0l + 32768;
    unsigned short* wt_pool1l = wt_pool1h + 32768;
    unsigned short* wt_c0h    = wt_pool1l + 32768;
    unsigned short* wt_c0l    = wt_c0h + 32768;
    unsigned short* wt_sc2h   = wt_c0l + 32768;
    unsigned short* wt_sc2l   = wt_sc2h + 32768;
    unsigned short* wt_sc3h   = wt_sc2l + 32768;
    unsigned short* wt_sc3l   = wt_sc3h + 32768;

    float* pmax = (float*)(misc + 2048 * 1024);
    float* psum = pmax + 32768;

    float* rowq2  = score;
    float* rowdq2 = (float*)newid;
    float* rowdiag = (float*)sel;

    float* s_sm  = BIG1;
    float* Tbuf  = BIG2;
    float* xd1   = BIG2;
    float* AX    = BIG2 + 2 * 1024 * 1024;
    float* s2sm  = BIG2 + 4 * 1024 * 1024;
    float* T2    = BIG2 + 6 * 1024 * 1024;
    float* outx2 = BIG1;
    float* adj2b = BIG1 + 1024 * 1024;
    float* xd2   = BIG1 + 2 * 1024 * 1024;
    float* sxA   = BIG1 + 3 * 1024 * 1024;
    float* sxE   = BIG1 + 5 * 1024 * 1024;
    float* sxB   = x0;
    float* sxC   = x0 + 2 * 1024 * 1024;
    float* sxD   = x0 + 3 * 1024 * 1024;

    char* adjc = (char*)adj1;
    int* elA  = (int*)(adjc + 0);
    int* elB  = (int*)(adjc + 2 * MBy);
    int* cntA = (int*)(adjc + 4 * MBy);                  // 128 KB
    int* cntB = (int*)(adjc + 4 * MBy + 128 * 1024);     // contiguous -> one memset
    int* offA = (int*)(adjc + 4 * MBy + 256 * 1024);
    int* curA = (int*)(adjc + 4 * MBy + 384 * 1024);
    int* offB = (int*)(adjc + 4 * MBy + 512 * 1024);
    int* curB = (int*)(adjc + 4 * MBy + 640 * 1024);
    char* aggc = (char*)agg;
    int* elC  = (int*)(aggc + 8 * MBy);
    int* elD  = (int*)(aggc + 10 * MBy);
    int* cntC = (int*)(aggc + 12 * MBy);
    int* offC = (int*)(aggc + 12 * MBy + 256 * 1024);
    int* curC = (int*)(aggc + 12 * MBy + 512 * 1024);
    int* cntD = (int*)(aggc + 13 * MBy);
    int* offD = (int*)(aggc + 13 * MBy + 256 * 1024);
    int* curD = (int*)(aggc + 13 * MBy + 512 * 1024);

    hipMemsetAsync(accs, 0, 520 * sizeof(float), stream);
    hipMemsetAsync(sxsum, 0, 16384 * sizeof(float), stream);
    hipMemsetAsync(cntA, 0, 65536 * sizeof(int), stream);   // cntA + cntB

    {
        WSpec a{sg1_wr, sg1_wrt, 128, 128, 128, wt_sg1h, wt_sg1l};
        WSpec b{sg2_wr, sg2_wrt, 128, 128, 128, wt_sg2h, wt_sg2l};
        WSpec c{pool0_w, nullptr, 128, 0, 256, wt_pool0h, wt_pool0l};
        WSpec d{pool1_w, nullptr, 128, 0, 128, wt_pool1h, wt_pool1l};
        WSpec e{conv0_wr, conv0_wrt, 128, 128, 128, wt_c0h, wt_c0l};
        WSpec f{sc2_wr, sc2_wrt, 128, 128, 128, wt_sc2h, wt_sc2l};
        WSpec g{sc3_wr, sc3_wrt, 128, 128, 128, wt_sc3h, wt_sc3l};
        wconv_all<<<dim3(128, 7), 256, 0, stream>>>(a, b, c, d, e, f, g);
    }

    edge_count2<<<dim3(2048, 2), 256, 0, stream>>>(dst, cntA, src, cntB);
    scan_offsets2<<<dim3(64, 2), 512, 0, stream>>>(cntA, offA, curA, cntB, offB, curB, 512, deg);
    edge_fill2<<<dim3(2048, 2), 256, 0, stream>>>(dst, src, curA, elA, src, dst, curB, elB);

    // ---- conv0 (split-bf16) ----
    gather_csr<<<4096, 256, 0, stream>>>(x, 128, offA, cntA, elA, agg, 32768, 512);
    gemm_aw<<<dim3(2, 512), 256, 0, stream>>>(agg, 128, x, 128, nullptr, wt_c0h, wt_c0l,
        conv0_b, x0, 128, 1);

    // ---- dense branch, pool 1 ----
    gemm_aw<<<dim3(4, 512), 256, 0, stream>>>(x0, 128, nullptr, 0, nullptr, wt_pool0h, wt_pool0l,
        pool0_b, s_sm, 256, 0);
    softmax_rows_wave<<<8192, 256, 0, stream>>>(s_sm, 256, deg, rowq2, rowdq2, 32768);
    reduce2_pergraph<<<64, 256, 0, stream>>>(rowq2, rowdq2, 512, accs + 128, accs + 64);
    gather_csr<<<8192, 256, 0, stream>>>(s_sm, 256, offB, cntB, elB, Tbuf, 32768, 512);
    gemm_tt<<<dim3(64, 4, 2), 256, 0, stream>>>(s_sm, x0, outx1, nullptr, 512, 256, 128, 0,
        512 * 256, 512 * 128, 256 * 128);
    gemm_tt<<<dim3(64, 4, 4), 256, 0, stream>>>(s_sm, Tbuf, adj1, accs + 192, 512, 256, 256, 1,
        512 * 256, 512 * 256, 256 * 256);
    zdiag_rowsum_wave<<<4096, 256, 0, stream>>>(adj1, 256, dpool, rowdiag, 16384);
    reduce2_pergraph<<<64, 256, 0, stream>>>(rowdiag, nullptr, 256, accs + 0, nullptr);
    norm_adj_wave<<<4096, 256, 0, stream>>>(adj1, 256, dpool, rowsum2, rscale2, 16384);
    // sage1
    gemm_nt<<<dim3(64, 4, 2), 256, 0, stream>>>(adj1, outx1, AX, 256, 128,
        256 * 256, 256 * 128, 256 * 128);
    gemm_aw<<<dim3(2, 256), 256, 0, stream>>>(AX, 128, outx1, 128, rscale2, wt_sg1h, wt_sg1l,
        sg1_b, xd1, 128, 1);
    // pool 2
    gemm_aw<<<dim3(2, 256), 256, 0, stream>>>(xd1, 128, nullptr, 0, nullptr, wt_pool1h, wt_pool1l,
        pool1_b, s2sm, 128, 0);
    softmax_rows_wave<<<4096, 256, 0, stream>>>(s2sm, 128, rowsum2, rowq2, rowdq2, 16384);
    reduce2_pergraph<<<64, 256, 0, stream>>>(rowq2, rowdq2, 256, accs + 384, accs + 320);
    gemm_nt<<<dim3(64, 4, 2), 256, 0, stream>>>(adj1, s2sm, T2, 256, 128,
        256 * 256, 256 * 128, 256 * 128);
    gemm_tt<<<dim3(64, 2, 2), 256, 0, stream>>>(s2sm, xd1, outx2, nullptr, 256, 128, 128, 0,
        256 * 128, 256 * 128, 128 * 128);
    gemm_tt<<<dim3(64, 2, 2), 256, 0, stream>>>(s2sm, T2, adj2b, accs + 448, 256, 128, 128, 1,
        256 * 128, 256 * 128, 128 * 128);
    zdiag_rowsum_wave<<<2048, 256, 0, stream>>>(adj2b, 128, dpool2, rowdiag, 8192);
    reduce2_pergraph<<<64, 256, 0, stream>>>(rowdiag, nullptr, 128, accs + 256, nullptr);
    norm_adj_wave<<<2048, 256, 0, stream>>>(adj2b, 128, dpool2, rowsum3, rscale3, 8192);
    // sage2 + head
    gemm_nt<<<dim3(64, 2, 2), 256, 0, stream>>>(adj2b, outx2, AX, 128, 128,
        128 * 128, 128 * 128, 128 * 128);
    gemm_aw<<<dim3(2, 128), 256, 0, stream>>>(AX, 128, outx2, 128, rscale3, wt_sg2h, wt_sg2l,
        sg2_b, xd2, 128, 0);
    mean_lin<<<64, 128, 0, stream>>>(xd2, l1_w, l1_b, xg, 128);

    // ---- sparse branch ----
    topk_kernel<<<64, 512, 0, stream>>>(x0, p1, 512, 256, newid, sel, gate);
    gather_gate<<<2048, 256, 0, stream>>>(x0, sel, gate, sxA, 16384);
    hipMemsetAsync(cntC, 0, 16384 * sizeof(int), stream);
    remap_edges_count<<<2048, 256, 0, stream>>>(src, dst, nullptr, newid, s1, d1, m1, cntC);
    readout_part<<<dim3(64, 4), 128, 0, stream>>>(sxA, 256, pmax, psum);
    readout_comb<<<64, 128, 0, stream>>>(pmax, psum, 256, sxsum);
    scan_offsets<<<64, 512, 0, stream>>>(cntC, offC, curC, 256, nullptr);
    edge_fill<<<2048, 256, 0, stream>>>(d1, s1, m1, curC, elC);
    gather_csr<<<2048, 256, 0, stream>>>(sxA, 128, offC, cntC, elC, agg, 16384, 256);
    gemm_aw<<<dim3(2, 256), 256, 0, stream>>>(agg, 128, sxA, 128, nullptr, wt_sc2h, wt_sc2l,
        sc2_b, sxB, 128, 1);
    topk_kernel<<<64, 512, 0, stream>>>(sxB, p2, 256, 128, newid, sel, gate);
    gather_gate<<<1024, 256, 0, stream>>>(sxB, sel, gate, sxC, 8192);
    hipMemsetAsync(cntD, 0, 8192 * sizeof(int), stream);
    remap_edges_count<<<2048, 256, 0, stream>>>(s1, d1, m1, newid, s2e, d2e, m2e, cntD);
    readout_part<<<dim3(64, 4), 128, 0, stream>>>(sxC, 128, pmax, psum);
    readout_comb<<<64, 128, 0, stream>>>(pmax, psum, 128, sxsum);
    scan_offsets<<<64, 512, 0, stream>>>(cntD, offD, curD, 128, nullptr);
    edge_fill<<<2048, 256, 0, stream>>>(d2e, s2e, m2e, curD, elD);
    gather_csr<<<1024, 256, 0, stream>>>(sxC, 128, offD, cntD, elD, agg, 8192, 128);
    gemm_aw<<<dim3(2, 128), 256, 0, stream>>>(agg, 128, sxC, 128, nullptr, wt_sc3h, wt_sc3l,
        sc3_b, sxD, 128, 1);
    topk_kernel<<<64, 512, 0, stream>>>(sxD, p3, 128, 64, newid, sel, gate);
    gather_gate<<<512, 256, 0, stream>>>(sxD, sel, gate, sxE, 4096);
    readout_part<<<dim3(64, 4), 128, 0, stream>>>(sxE, 64, pmax, psum);
    readout_comb<<<64, 128, 0, stream>>>(pmax, psum, 64, sxsum);

    final_head<<<64, 128, 0, stream>>>(sxsum, l11_w, l11_b, xg, l2_w, l2_b, accs, out);
}